// Round 7
// baseline (269.767 us; speedup 1.0000x reference)
//
#include <hip/hip_runtime.h>

#define B_ROWS 4096
#define N_ROWS 8192
#define DDIM   256
#define IT2    2.885390081777927f   /* 1/(T*ln2), T=0.5 */

#define NTILE    64                 /* 8192 / 128 */
#define NBLK_MAIN 2048              /* 64 rt x 32 split; 2 cts per block */

typedef unsigned short ushort_t;
typedef __bf16 bf16x8 __attribute__((ext_vector_type(8)));
typedef float  f32x4  __attribute__((ext_vector_type(4)));

__device__ __forceinline__ ushort_t f2bf(float x) {
    union { float f; unsigned u; } a; a.f = x;
    unsigned r = a.u + 0x7fffu + ((a.u >> 16) & 1u);   /* RNE */
    return (ushort_t)(r >> 16);
}

__device__ __forceinline__ void gload_lds16(const void* g, void* l) {
    __builtin_amdgcn_global_load_lds(
        (const __attribute__((address_space(1))) unsigned int*)g,
        (__attribute__((address_space(3))) unsigned int*)l,
        16, 0, 0);
}

/* ---- kernel A: normalize -> bf16 Xb; pos; zero den/ticket -------------- */
__global__ __launch_bounds__(256) void k_prep(
        const float* __restrict__ feats, const float* __restrict__ tfeats,
        ushort_t* __restrict__ Xb, float* __restrict__ posv,
        float* __restrict__ den4, int* __restrict__ ticket) {
    __shared__ float fbuf[2][DDIM];
    __shared__ float nsh[4];
    int w = threadIdx.x >> 6, l = threadIdx.x & 63;
    int bid = blockIdx.x;
    int i0 = bid * 2;                                /* grid 2048 */

    /* zero-init den4[4][8192] + ticket (ws is poisoned 0xAA) */
    int z = bid * 256 + threadIdx.x;
    if (z < 4 * N_ROWS) den4[z] = 0.0f;
    if (z == 4 * N_ROWS) *ticket = 0;

    int pair = (w < 2) ? w : (w - 2);
    int row  = (w < 2) ? (i0 + pair) : (i0 + pair + B_ROWS);
    const float* src = (w < 2) ? feats + (size_t)(i0 + pair) * DDIM
                               : tfeats + (size_t)(i0 + pair) * DDIM;
    float4 v = ((const float4*)src)[l];
    float ss = v.x*v.x + v.y*v.y + v.z*v.z + v.w*v.w;
    #pragma unroll
    for (int m = 1; m < 64; m <<= 1) ss += __shfl_xor(ss, m);
    float nrm = fmaxf(sqrtf(ss), 1e-12f);
    float inv = 1.0f / nrm;
    ushort4 o;
    o.x = f2bf(v.x * inv); o.y = f2bf(v.y * inv);
    o.z = f2bf(v.z * inv); o.w = f2bf(v.w * inv);
    ((ushort4*)(Xb + (size_t)row * DDIM))[l] = o;
    if (w < 2) ((float4*)fbuf[pair])[l] = v;
    if (l == 0) nsh[w] = nrm;
    __syncthreads();
    if (w >= 2) {
        float4 a = ((const float4*)fbuf[pair])[l];
        float d = a.x*v.x + a.y*v.y + a.z*v.z + a.w*v.w;
        #pragma unroll
        for (int m = 1; m < 64; m <<= 1) d += __shfl_xor(d, m);
        if (l == 0) posv[i0 + pair] = d / (nsh[pair] * nsh[w]);
    }
}

/* ---- kernel B: R1-mapped GEMM, lower-tri skip, atomic den, ticket tail - */
__global__ __launch_bounds__(256) void k_main(
        const ushort_t* __restrict__ Xb, const float* __restrict__ posv,
        float* __restrict__ den4, int* __restrict__ ticket,
        float* __restrict__ out) {
    __shared__ ushort_t ldsA[128 * 64];     /* 16 KB, swizzled content */
    __shared__ ushort_t ldsB[128 * 64];     /* 16 KB */
    __shared__ float red[4];
    __shared__ int islast;

    const int t = threadIdx.x, l = t & 63, w = t >> 6;
    const int wm = w >> 1, wn = w & 1;

    /* R1 mapping: 2 adjacent col-tiles per block, same A panel (L1/L2 warm
       on the 2nd ct). Skip lower-triangle tiles (symmetry). */
    const int rt = blockIdx.x >> 5;
    const int split = blockIdx.x & 31;
    const int rowbase = rt * 128;

    #pragma unroll 1
    for (int ctk = 0; ctk < 2; ++ctk) {
        const int ct = split * 2 + ctk;
        if (ct < rt) continue;                      /* lower triangle: skip */
        const bool isdiag = (ct == rt);
        const int colbase = ct * 128;

        f32x4 acc[4][4];
        #pragma unroll
        for (int m = 0; m < 4; m++)
            #pragma unroll
            for (int n = 0; n < 4; n++) acc[m][n] = (f32x4){0.f, 0.f, 0.f, 0.f};

        for (int kb = 0; kb < DDIM; kb += 64) {
            /* stage A[128][64], B[128][64]; pre-swizzled source so the
               linear global_load_lds dest matches the XOR-swizzled read */
            #pragma unroll
            for (int i = 0; i < 4; i++) {
                int o   = (i * 256 + t) * 16;
                int row = o >> 7;
                int cb  = o & 127;
                int scb = cb ^ ((row & 7) << 4);
                gload_lds16((const char*)Xb +
                            ((size_t)(rowbase + row) * DDIM + kb) * 2 + scb,
                            (char*)ldsA + o);
                gload_lds16((const char*)Xb +
                            ((size_t)(colbase + row) * DDIM + kb) * 2 + scb,
                            (char*)ldsB + o);
            }
            __syncthreads();

            #pragma unroll
            for (int ks = 0; ks < 2; ks++) {
                bf16x8 af[4], bfr[4];
                int cbw = ((l >> 4) * 16) + ks * 64;
                #pragma unroll
                for (int m = 0; m < 4; m++) {
                    int row  = wm * 64 + m * 16 + (l & 15);
                    int addr = row * 128 + (cbw ^ ((row & 7) << 4));
                    af[m] = *(const bf16x8*)((const char*)ldsA + addr);
                }
                #pragma unroll
                for (int n = 0; n < 4; n++) {
                    int row  = wn * 64 + n * 16 + (l & 15);
                    int addr = row * 128 + (cbw ^ ((row & 7) << 4));
                    bfr[n] = *(const bf16x8*)((const char*)ldsB + addr);
                }
                #pragma unroll
                for (int m = 0; m < 4; m++)
                    #pragma unroll
                    for (int n = 0; n < 4; n++)
                        acc[m][n] = __builtin_amdgcn_mfma_f32_16x16x32_bf16(
                            af[m], bfr[n], acc[m][n], 0, 0, 0);
            }
            __syncthreads();
        }

        /* epilogue: e = exp2(sim*IT2); diag tile -> 1.0 on the diagonal */
        float rs[4][4];
        float cs[4] = {0.f, 0.f, 0.f, 0.f};
        #pragma unroll
        for (int m = 0; m < 4; m++)
            #pragma unroll
            for (int j = 0; j < 4; j++) rs[m][j] = 0.0f;

        #pragma unroll
        for (int m = 0; m < 4; m++) {
            #pragma unroll
            for (int j = 0; j < 4; j++) {
                int grow = rowbase + wm * 64 + m * 16 + (l >> 4) * 4 + j;
                #pragma unroll
                for (int n = 0; n < 4; n++) {
                    int gcol = colbase + wn * 64 + n * 16 + (l & 15);
                    float e = exp2f(acc[m][n][j] * IT2);
                    if (isdiag && grow == gcol) e = 1.0f;
                    rs[m][j] += e;
                    cs[n]    += e;
                }
            }
        }

        /* row sums -> den4[wn] (fire-and-forget atomics) */
        #pragma unroll
        for (int m = 0; m < 4; m++)
            #pragma unroll
            for (int j = 0; j < 4; j++) {
                float v = rs[m][j];
                v += __shfl_xor(v, 1); v += __shfl_xor(v, 2);
                v += __shfl_xor(v, 4); v += __shfl_xor(v, 8);
                if ((l & 15) == 0) {
                    int grow = rowbase + wm * 64 + m * 16 + (l >> 4) * 4 + j;
                    atomicAdd(&den4[(size_t)wn * N_ROWS + grow], v);
                }
            }

        /* col sums -> den4[2+wm] (symmetry; skip on diag to avoid dbl-count) */
        if (!isdiag) {
            #pragma unroll
            for (int n = 0; n < 4; n++) {
                float v = cs[n];
                v += __shfl_xor(v, 16);
                v += __shfl_xor(v, 32);
                if (l < 16) {
                    int gcol = colbase + wn * 64 + n * 16 + l;
                    atomicAdd(&den4[(size_t)(2 + wm) * N_ROWS + gcol], v);
                }
            }
        }
    }

    /* ---- ticket: last block (of ALL 2048) computes the scalar tail ----- */
    __threadfence();
    if (t == 0) islast = (atomicAdd(ticket, 1) == NBLK_MAIN - 1);
    __syncthreads();
    if (!islast) return;

    float lsum = 0.0f;
    for (int r = t; r < N_ROWS; r += 256) {
        float d = 0.0f;
        #pragma unroll
        for (int s = 0; s < 4; s++)
            d += __hip_atomic_load(&den4[(size_t)s * N_ROWS + r],
                                   __ATOMIC_RELAXED, __HIP_MEMORY_SCOPE_AGENT);
        lsum += logf(d);
    }
    float psum = 0.0f;
    for (int i = t; i < B_ROWS; i += 256) psum += posv[i];
    /* total = sum(log den) - (1/T)*sum(pos); sum(pos)=2*sum(posv), 1/T=2 */
    float comb = lsum - 4.0f * psum;
    #pragma unroll
    for (int m = 1; m < 64; m <<= 1) comb += __shfl_xor(comb, m);
    if (l == 0) red[w] = comb;
    __syncthreads();
    if (t == 0) out[0] = (red[0] + red[1] + red[2] + red[3]) / (float)N_ROWS;
}

extern "C" void kernel_launch(void* const* d_in, const int* in_sizes, int n_in,
                              void* d_out, int out_size, void* d_ws, size_t ws_size,
                              hipStream_t stream) {
    const float* feats  = (const float*)d_in[0];
    const float* tfeats = (const float*)d_in[1];
    float* out = (float*)d_out;
    char* ws = (char*)d_ws;

    ushort_t* Xb     = (ushort_t*)ws;                   /* 4 MB              */
    float*    posv   = (float*)(ws + 4194304);          /* 16 KB             */
    float*    den4   = (float*)(ws + 4210688);          /* 4*8192*4 = 128 KB */
    int*      ticket = (int*)(ws + 4341760);            /* 4 B               */

    k_prep<<<B_ROWS / 2, 256, 0, stream>>>(feats, tfeats, Xb, posv, den4, ticket);
    k_main<<<NBLK_MAIN, 256, 0, stream>>>(Xb, posv, den4, ticket, out);
}